// Round 20
// baseline (608.408 us; speedup 1.0000x reference)
//
#include <hip/hip_runtime.h>

#define NN 100000
#define EE 1600000

using bf16x8 = __attribute__((ext_vector_type(8))) short;
using f32x4  = __attribute__((ext_vector_type(4))) float;

static __device__ __forceinline__ unsigned short f2bh(float f) {
    unsigned int u = __float_as_uint(f);
    return (unsigned short)((u + 0x7FFFu + ((u >> 16) & 1u)) >> 16);
}
static __device__ __forceinline__ float bh2f(unsigned short h) {
    return __uint_as_float(((unsigned int)h) << 16);
}

// split 8 floats into hi/lo bf16x8 via truncation (residual exact in fp32)
static __device__ __forceinline__ void split_pack(float4 a, float4 b,
                                                  bf16x8& h, bf16x8& l) {
    float f[8] = {a.x, a.y, a.z, a.w, b.x, b.y, b.z, b.w};
    union { bf16x8 v; unsigned int u[4]; } H, L;
    #pragma unroll
    for (int e = 0; e < 4; ++e) {
        unsigned int u0 = __float_as_uint(f[2 * e]);
        unsigned int u1 = __float_as_uint(f[2 * e + 1]);
        H.u[e] = (u0 >> 16) | (u1 & 0xFFFF0000u);
        float r0 = f[2 * e]     - __uint_as_float(u0 & 0xFFFF0000u);
        float r1 = f[2 * e + 1] - __uint_as_float(u1 & 0xFFFF0000u);
        L.u[e] = (__float_as_uint(r0) >> 16) | (__float_as_uint(r1) & 0xFFFF0000u);
    }
    h = H.v; l = L.v;
}

// ------- fused prep: Wg1 chunked image (BK=32) + Wf2 transpose + cursor -----
__global__ __launch_bounds__(256) void k_prep(const float* __restrict__ Wg1,
        const float* __restrict__ Wf2,
        unsigned short* __restrict__ w1img,
        unsigned short* __restrict__ w2h, unsigned short* __restrict__ w2l,
        unsigned int* __restrict__ cursor) {
    int t = blockIdx.x * 256 + threadIdx.x;
    if (t < 65536) {
        int k = t >> 6, c = t & 63;
        float f = Wg1[t];
        unsigned short hh = f2bh(f);
        int chunk = k >> 5, kk = k & 31;
        size_t base = (size_t)chunk * 4608 + (size_t)c * 36 + kk;   // u16 units
        w1img[base] = hh;
        w1img[base + 2304] = f2bh(f - bh2f(hh));
    } else if (t < 131072) {
        int tt = t - 65536;
        int k = tt >> 10, c = tt & 1023;
        float f = Wf2[tt];
        unsigned short hh = f2bh(f);
        w2h[c * 64 + k] = hh;
        w2l[c * 64 + k] = f2bh(f - bh2f(hh));
    } else if (t < 131072 + NN) {
        cursor[t - 131072] = 0u;
    }
}

// -------- bucket fill: bkt[d*64 + pos] = src; cursor ends as degree ---------
__global__ __launch_bounds__(256) void k_fill(const int* __restrict__ src,
        const int* __restrict__ dst, unsigned int* cursor, int* __restrict__ bkt) {
    int e = blockIdx.x * 256 + threadIdx.x;
    if (e < EE) {
        int d = dst[e];
        unsigned int pos = atomicAdd(&cursor[d], 1u);
        bkt[(size_t)d * 64 + pos] = src[e];
    }
}

// -------- bucket sort (64-lane bitonic) + dinv; canonical order -------------
__global__ __launch_bounds__(256) void k_sort(int* __restrict__ bkt,
        const unsigned int* __restrict__ deg, float* __restrict__ dinv) {
    int v = (blockIdx.x * 256 + threadIdx.x) >> 6;
    int lane = threadIdx.x & 63;
    if (v >= NN) return;
    int n = (int)deg[v];
    if (lane == 0) dinv[v] = rsqrtf((float)(n + 1));
    int val = (lane < n) ? bkt[(size_t)v * 64 + lane] : 0x7FFFFFFF;
    #pragma unroll
    for (int k = 2; k <= 64; k <<= 1) {
        #pragma unroll
        for (int j = k >> 1; j > 0; j >>= 1) {
            int partner = __shfl_xor(val, j, 64);
            bool takeMin = (((lane & k) == 0) == ((lane & j) == 0));
            val = takeMin ? min(val, partner) : max(val, partner);
        }
    }
    if (lane < n) bkt[(size_t)v * 64 + lane] = val;
}

// ------- GEMM1 v10: v5 + counted-vmcnt barrier (no sched_barrier) -----------
// x-loads issue unconditionally (clamped addr) so per-wave vmcnt counts are
// exact: wave0 = 3 stage + 2 x, waves1-3 = 2 stage + 2 x. vmcnt(2) at the
// barrier retires all stage loads, keeps the 2 x-loads of chunk t+1 in flight.
__global__ __launch_bounds__(256) void k_gemm1(const float* __restrict__ x,
        const unsigned short* __restrict__ wimg,
        const float* __restrict__ dinv, unsigned short* __restrict__ g1b) {
    __shared__ __align__(16) unsigned short bs[2][2][64][36];   // 18432 B
    const int tid = threadIdx.x;
    const int lane = tid & 63, w = tid >> 6;
    const int l16 = lane & 15, g = lane >> 4;
    const int row0 = blockIdx.x * 64;
    const int rA = row0 + w * 16 + l16;
    const int rClamp = rA < NN ? rA : NN - 1;
    const float* xp = x + (size_t)rClamp * 1024 + g * 8;
    const char* wb = (const char*)wimg;
    f32x4 acc[4] = {};
    for (int j = w; j < 9; j += 4)
        __builtin_amdgcn_global_load_lds((const unsigned int*)(wb + j * 1024 + lane * 16),
                                         (unsigned int*)((char*)&bs[0][0][0][0] + j * 1024), 16, 0, 0);
    float4 xr0 = *(const float4*)(xp);
    float4 xr1 = *(const float4*)(xp + 4);
    __syncthreads();
    int cur = 0;
    for (int t = 0; t < 32; ++t) {
        float4 nx0, nx1;
        if (t < 31) {
            const char* gb = wb + (size_t)(t + 1) * 9216;
            char* lb = (char*)&bs[cur ^ 1][0][0][0];
            for (int j = w; j < 9; j += 4)
                __builtin_amdgcn_global_load_lds((const unsigned int*)(gb + j * 1024 + lane * 16),
                                                 (unsigned int*)(lb + j * 1024), 16, 0, 0);
            nx0 = *(const float4*)(xp + (t + 1) * 32);
            nx1 = *(const float4*)(xp + (t + 1) * 32 + 4);
        }
        bf16x8 ah, al;
        split_pack(xr0, xr1, ah, al);
        #pragma unroll
        for (int nf = 0; nf < 4; ++nf) {
            bf16x8 bh = *(const bf16x8*)&bs[cur][0][nf * 16 + l16][g * 8];
            bf16x8 bl = *(const bf16x8*)&bs[cur][1][nf * 16 + l16][g * 8];
            acc[nf] = __builtin_amdgcn_mfma_f32_16x16x32_bf16(ah, bh, acc[nf], 0, 0, 0);
            acc[nf] = __builtin_amdgcn_mfma_f32_16x16x32_bf16(al, bh, acc[nf], 0, 0, 0);
            acc[nf] = __builtin_amdgcn_mfma_f32_16x16x32_bf16(ah, bl, acc[nf], 0, 0, 0);
        }
        if (t < 31) {
            // retire this iter's stage loads; keep the 2 x-loads in flight
            asm volatile("s_waitcnt vmcnt(2)" ::: "memory");
            __builtin_amdgcn_s_barrier();
            xr0 = nx0; xr1 = nx1;
        }
        cur ^= 1;
    }
    #pragma unroll
    for (int r = 0; r < 4; ++r) {
        int node = row0 + w * 16 + g * 4 + r;
        if (node < NN) {
            float di = dinv[node];
            #pragma unroll
            for (int nf = 0; nf < 4; ++nf)
                g1b[(size_t)node * 64 + nf * 16 + l16] = f2bh(acc[nf][r] * di);
        }
    }
}

// ------- gather 64ch (bf16, half-wave/node): h = relu(dinv*sum + bg1) -------
__global__ __launch_bounds__(256) void k_gather64(const unsigned short* __restrict__ g1b,
        const int* __restrict__ bkt, const unsigned int* __restrict__ deg,
        const float* __restrict__ dinv, const float* __restrict__ bg1,
        float* __restrict__ h) {
    int node = (blockIdx.x * 256 + threadIdx.x) >> 5;   // half-wave = node
    int c = threadIdx.x & 31;                            // channel pair id
    if (node >= NN) return;
    unsigned int n = deg[node];
    const int* b = bkt + (size_t)node * 64;
    const unsigned int* gp = (const unsigned int*)g1b;   // [node][32] uints
    unsigned int self = gp[(size_t)node * 32 + c];
    float sum0 = bh2f((unsigned short)self);
    float sum1 = bh2f((unsigned short)(self >> 16));
    unsigned int i = 0;
    for (; i + 4 <= n; i += 4) {
        int4 s4 = *(const int4*)(b + i);                 // broadcast load
        unsigned int v0 = gp[(size_t)s4.x * 32 + c];
        unsigned int v1 = gp[(size_t)s4.y * 32 + c];
        unsigned int v2 = gp[(size_t)s4.z * 32 + c];
        unsigned int v3 = gp[(size_t)s4.w * 32 + c];
        sum0 += (bh2f((unsigned short)v0) + bh2f((unsigned short)v1))
              + (bh2f((unsigned short)v2) + bh2f((unsigned short)v3));
        sum1 += (bh2f((unsigned short)(v0 >> 16)) + bh2f((unsigned short)(v1 >> 16)))
              + (bh2f((unsigned short)(v2 >> 16)) + bh2f((unsigned short)(v3 >> 16)));
    }
    for (; i < n; ++i) {
        unsigned int v = gp[(size_t)b[i] * 32 + c];
        sum0 += bh2f((unsigned short)v);
        sum1 += bh2f((unsigned short)(v >> 16));
    }
    float di = dinv[node];
    float2 bb = *(const float2*)(bg1 + 2 * c);
    float2 o;
    o.x = fmaxf(sum0 * di + bb.x, 0.f);
    o.y = fmaxf(sum1 * di + bb.y, 0.f);
    *(float2*)(h + (size_t)node * 64 + 2 * c) = o;
}

// ------- layer2 GEMM (fp32): g2b = bf16((h @ Wg2) * dinv[row]) --------------
__global__ __launch_bounds__(256) void k_layer2(const float* __restrict__ h,
        const float* __restrict__ Wg2, const float* __restrict__ dinv,
        unsigned short* __restrict__ g2b) {
    __shared__ __align__(16) float as[64][68];
    __shared__ __align__(16) float wsh[64][32];
    const int tid = threadIdx.x;
    const int node0 = blockIdx.x * 64;
    {
        const int lr = tid >> 4, lk = (tid & 15) * 4;
        #pragma unroll
        for (int l = 0; l < 4; ++l) {
            int r = lr + l * 16, v = node0 + r;
            float4 a = make_float4(0.f, 0.f, 0.f, 0.f);
            if (v < NN) a = *(const float4*)(h + (size_t)v * 64 + lk);
            *(float4*)&as[r][lk] = a;
        }
        const int wr = tid >> 3, wk = (tid & 7) * 4;
        #pragma unroll
        for (int l = 0; l < 2; ++l) {
            int r = wr + l * 32;
            *(float4*)&wsh[r][wk] = *(const float4*)(Wg2 + (size_t)r * 32 + wk);
        }
    }
    __syncthreads();
    const int tx = tid & 7, ty = tid >> 3;
    float acc[2][4] = {{0.f}};
    for (int kk = 0; kk < 64; kk += 4) {
        float wv[4][4];
        #pragma unroll
        for (int j = 0; j < 4; ++j)
            *(float4*)&wv[j][0] = *(const float4*)&wsh[kk + j][tx * 4];
        #pragma unroll
        for (int i = 0; i < 2; ++i) {
            float xv[4];
            *(float4*)&xv[0] = *(const float4*)&as[ty * 2 + i][kk];
            #pragma unroll
            for (int j = 0; j < 4; ++j) {
                #pragma unroll
                for (int c = 0; c < 4; ++c)
                    acc[i][c] += xv[j] * wv[j][c];
            }
        }
    }
    #pragma unroll
    for (int i = 0; i < 2; ++i) {
        int v = node0 + ty * 2 + i;
        if (v < NN) {
            float di = dinv[v];
            unsigned int p0 = (unsigned int)f2bh(acc[i][0] * di)
                            | ((unsigned int)f2bh(acc[i][1] * di) << 16);
            unsigned int p1 = (unsigned int)f2bh(acc[i][2] * di)
                            | ((unsigned int)f2bh(acc[i][3] * di) << 16);
            *(uint2*)(g2b + (size_t)v * 32 + tx * 4) = make_uint2(p0, p1);
        }
    }
}

// ------- gather 32ch (bf16, quarter-wave/node): z = dinv*sum + bg2 ----------
__global__ __launch_bounds__(256) void k_gather32(const unsigned short* __restrict__ g2b,
        const int* __restrict__ bkt, const unsigned int* __restrict__ deg,
        const float* __restrict__ dinv, const float* __restrict__ bg2,
        float* __restrict__ z) {
    int node = (blockIdx.x * 256 + threadIdx.x) >> 4;   // quarter-wave = node
    int c = threadIdx.x & 15;                            // channel pair id
    if (node >= NN) return;
    unsigned int n = deg[node];
    const int* b = bkt + (size_t)node * 64;
    const unsigned int* gp = (const unsigned int*)g2b;   // [node][16] uints
    unsigned int self = gp[(size_t)node * 16 + c];
    float sum0 = bh2f((unsigned short)self);
    float sum1 = bh2f((unsigned short)(self >> 16));
    unsigned int i = 0;
    for (; i + 4 <= n; i += 4) {
        int4 s4 = *(const int4*)(b + i);
        unsigned int v0 = gp[(size_t)s4.x * 16 + c];
        unsigned int v1 = gp[(size_t)s4.y * 16 + c];
        unsigned int v2 = gp[(size_t)s4.z * 16 + c];
        unsigned int v3 = gp[(size_t)s4.w * 16 + c];
        sum0 += (bh2f((unsigned short)v0) + bh2f((unsigned short)v1))
              + (bh2f((unsigned short)v2) + bh2f((unsigned short)v3));
        sum1 += (bh2f((unsigned short)(v0 >> 16)) + bh2f((unsigned short)(v1 >> 16)))
              + (bh2f((unsigned short)(v2 >> 16)) + bh2f((unsigned short)(v3 >> 16)));
    }
    for (; i < n; ++i) {
        unsigned int v = gp[(size_t)b[i] * 16 + c];
        sum0 += bh2f((unsigned short)v);
        sum1 += bh2f((unsigned short)(v >> 16));
    }
    float di = dinv[node];
    float2 bb = *(const float2*)(bg2 + 2 * c);
    float2 o;
    o.x = sum0 * di + bb.x;
    o.y = sum1 * di + bb.y;
    *(float2*)(z + (size_t)node * 32 + 2 * c) = o;
}

// ---------------- decode v3 (r9/r15-measured): 16 chunks x 64 cols ----------
__global__ __launch_bounds__(256) void k_decode(const float* __restrict__ z,
        const float* __restrict__ Wf1, const float* __restrict__ bf1,
        const unsigned short* __restrict__ w2hg, const unsigned short* __restrict__ w2lg,
        const float* __restrict__ bf2, float* __restrict__ out) {
    __shared__ __align__(16) unsigned char smem[35328];
    float (*dsh)[68] = (float (*)[68])smem;                          // 64x68 f
    float (*zs)[36]  = (float (*)[36])(smem + 17408);                // 64x36 f
    float (*w1s)[64] = (float (*)[64])(smem + 26624);                // 32x64 f
    unsigned short (*w2h)[72] = (unsigned short (*)[72])smem;        // 64x72 u16
    unsigned short (*w2l)[72] = (unsigned short (*)[72])(smem + 9216);
    float (*ost)[66] = (float (*)[66])(smem + 18432);                // 64x66 f
    const int tid = threadIdx.x;
    const int lane = tid & 63, w = tid >> 6;
    const int l16 = lane & 15, g = lane >> 4;
    const int node0 = blockIdx.x * 64;

    uint4 ph[2], pl[2];
    #pragma unroll
    for (int j = 0; j < 2; ++j) {
        int fi = tid + 256 * j;
        int c = fi >> 3, k8 = (fi & 7) * 8;
        ph[j] = *(const uint4*)(w2hg + (size_t)c * 64 + k8);
        pl[j] = *(const uint4*)(w2lg + (size_t)c * 64 + k8);
    }

    #pragma unroll
    for (int j = 0; j < 2; ++j) {
        int fi = tid + 256 * j;
        int v = fi >> 3, m4 = (fi & 7) * 4;
        float4 zz = make_float4(0.f, 0.f, 0.f, 0.f);
        if (node0 + v < NN) zz = *(const float4*)(z + (size_t)(node0 + v) * 32 + m4);
        *(float4*)&zs[v][m4] = zz;
    }
    #pragma unroll
    for (int j = 0; j < 2; ++j) {
        int fi = tid + 256 * j;
        int r = fi >> 4, c4 = (fi & 15) * 4;
        *(float4*)&w1s[r][c4] = *(const float4*)(Wf1 + (size_t)r * 64 + c4);
    }
    __syncthreads();

    {
        const int dtx = tid & 15, dty = tid >> 4;
        float acc[4][4] = {{0.f}};
        for (int m = 0; m < 32; m += 4) {
            float wv[4][4];
            #pragma unroll
            for (int j = 0; j < 4; ++j)
                *(float4*)&wv[j][0] = *(const float4*)&w1s[m + j][dtx * 4];
            #pragma unroll
            for (int i = 0; i < 4; ++i) {
                float zv[4];
                *(float4*)&zv[0] = *(const float4*)&zs[dty * 4 + i][m];
                #pragma unroll
                for (int j = 0; j < 4; ++j) {
                    #pragma unroll
                    for (int c = 0; c < 4; ++c)
                        acc[i][c] += zv[j] * wv[j][c];
                }
            }
        }
        float4 b4 = *(const float4*)(bf1 + dtx * 4);
        #pragma unroll
        for (int i = 0; i < 4; ++i) {
            float4 dd;
            dd.x = fmaxf(acc[i][0] + b4.x, 0.f);
            dd.y = fmaxf(acc[i][1] + b4.y, 0.f);
            dd.z = fmaxf(acc[i][2] + b4.z, 0.f);
            dd.w = fmaxf(acc[i][3] + b4.w, 0.f);
            *(float4*)&dsh[dty * 4 + i][dtx * 4] = dd;
        }
    }
    __syncthreads();

    bf16x8 ah[2], al[2];
    {
        int row = w * 16 + l16;
        #pragma unroll
        for (int s = 0; s < 2; ++s) {
            int k0 = s * 32 + g * 8;
            float4 f0 = *(float4*)&dsh[row][k0];
            float4 f1 = *(float4*)&dsh[row][k0 + 4];
            float fv[8] = {f0.x, f0.y, f0.z, f0.w, f1.x, f1.y, f1.z, f1.w};
            bf16x8 hv, lv;
            #pragma unroll
            for (int e = 0; e < 8; ++e) {
                unsigned short hh = f2bh(fv[e]);
                hv[e] = (short)hh;
                lv[e] = (short)f2bh(fv[e] - bh2f(hh));
            }
            ah[s] = hv; al[s] = lv;
        }
    }
    __syncthreads();

    #pragma unroll
    for (int j = 0; j < 2; ++j) {
        int fi = tid + 256 * j;
        int c = fi >> 3, k8 = (fi & 7) * 8;
        *(uint4*)&w2h[c][k8] = ph[j];
        *(uint4*)&w2l[c][k8] = pl[j];
        ph[j] = *(const uint4*)(w2hg + (size_t)(64 + c) * 64 + k8);
        pl[j] = *(const uint4*)(w2lg + (size_t)(64 + c) * 64 + k8);
    }
    __syncthreads();

    for (int ch = 0; ch < 16; ++ch) {
        const int col0 = ch * 64;
        f32x4 acc[4] = {};
        #pragma unroll
        for (int nf = 0; nf < 4; ++nf) {
            int c = nf * 16 + l16;
            #pragma unroll
            for (int s = 0; s < 2; ++s) {
                int k0 = s * 32 + g * 8;
                bf16x8 bh = *(const bf16x8*)&w2h[c][k0];
                bf16x8 bl = *(const bf16x8*)&w2l[c][k0];
                acc[nf] = __builtin_amdgcn_mfma_f32_16x16x32_bf16(ah[s], bh, acc[nf], 0, 0, 0);
                acc[nf] = __builtin_amdgcn_mfma_f32_16x16x32_bf16(al[s], bh, acc[nf], 0, 0, 0);
                acc[nf] = __builtin_amdgcn_mfma_f32_16x16x32_bf16(ah[s], bl, acc[nf], 0, 0, 0);
            }
        }
        #pragma unroll
        for (int nf = 0; nf < 4; ++nf) {
            float b = bf2[col0 + nf * 16 + l16];
            #pragma unroll
            for (int r = 0; r < 4; ++r)
                ost[w * 16 + g * 4 + r][nf * 16 + l16] = fmaxf(acc[nf][r] + b, 0.f);
        }
        __syncthreads();
        if (ch < 15) {
            #pragma unroll
            for (int j = 0; j < 2; ++j) {
                int fi = tid + 256 * j;
                int c = fi >> 3, k8 = (fi & 7) * 8;
                *(uint4*)&w2h[c][k8] = ph[j];
                *(uint4*)&w2l[c][k8] = pl[j];
                if (ch < 14) {
                    ph[j] = *(const uint4*)(w2hg + (size_t)((ch + 2) * 64 + c) * 64 + k8);
                    pl[j] = *(const uint4*)(w2lg + (size_t)((ch + 2) * 64 + c) * 64 + k8);
                }
            }
        }
        #pragma unroll
        for (int j = 0; j < 4; ++j) {
            int fi = tid + 256 * j;
            int row = fi >> 4, c4 = (fi & 15) * 4;
            int node = node0 + row;
            if (node < NN) {
                float4 o = *(float4*)&ost[row][c4];
                *(float4*)(out + (size_t)node * 1024 + col0 + c4) = o;
            }
        }
        __syncthreads();
    }
}

extern "C" void kernel_launch(void* const* d_in, const int* in_sizes, int n_in,
                              void* d_out, int out_size, void* d_ws, size_t ws_size,
                              hipStream_t stream) {
    const float* x   = (const float*)d_in[0];
    const int* ei    = (const int*)d_in[1];
    const float* Wg1 = (const float*)d_in[2];
    const float* bg1 = (const float*)d_in[3];
    const float* Wg2 = (const float*)d_in[4];
    const float* bg2 = (const float*)d_in[5];
    const float* Wf1 = (const float*)d_in[6];
    const float* bf1 = (const float*)d_in[7];
    const float* Wf2 = (const float*)d_in[8];
    const float* bf2 = (const float*)d_in[9];
    float* out = (float*)d_out;
    float* ws  = (float*)d_ws;

    const int* src = ei;
    const int* dst = ei + EE;

    // ws (26 MB): dinv | g2b | z | Wf2T split tables
    float* dinv = ws;
    unsigned short* g2b = (unsigned short*)(ws + NN);              // 32N u16
    float* z    = ws + NN + 16 * NN;
    unsigned short* wf2h = (unsigned short*)(ws + NN + 16 * NN + 32 * NN);  // 64K u16
    unsigned short* wf2l = wf2h + 64 * 1024;                       // 64K u16

    // d_out scratch (all dead before k_decode writes out):
    unsigned short* g1b = (unsigned short*)out;            // 64N u16
    float* h  = out + (size_t)32 * NN;                     // 64N floats
    int* bkt  = (int*)(out + (size_t)96 * NN);             // 64N ints (cap 64)
    unsigned int* cursor = (unsigned int*)(bkt + (size_t)64 * NN);  // N (= degree)
    unsigned short* wg1img = (unsigned short*)(cursor + NN);        // 147456 u16

    k_prep  <<<(131072 + NN + 255) / 256, 256, 0, stream>>>(Wg1, Wf2, wg1img, wf2h, wf2l, cursor);
    k_fill  <<<(EE + 255) / 256, 256, 0, stream>>>(src, dst, cursor, bkt);
    k_sort  <<<(NN * 64 + 255) / 256, 256, 0, stream>>>(bkt, cursor, dinv);
    k_gemm1 <<<(NN + 63) / 64, 256, 0, stream>>>(x, wg1img, dinv, g1b);
    k_gather64<<<(NN * 32 + 255) / 256, 256, 0, stream>>>(g1b, bkt, cursor, dinv, bg1, h);
    k_layer2<<<(NN + 63) / 64, 256, 0, stream>>>(h, Wg2, dinv, g2b);
    k_gather32<<<(NN * 16 + 255) / 256, 256, 0, stream>>>(g2b, bkt, cursor, dinv, bg2, z);
    k_decode<<<(NN + 63) / 64, 256, 0, stream>>>(z, Wf1, bf1, wf2h, wf2l, bf2, out);
}

// Round 21
// 577.527 us; speedup vs baseline: 1.0535x; 1.0535x over previous
//
#include <hip/hip_runtime.h>

#define NN 100000
#define EE 1600000

using bf16x8 = __attribute__((ext_vector_type(8))) short;
using f32x4  = __attribute__((ext_vector_type(4))) float;

static __device__ __forceinline__ unsigned short f2bh(float f) {
    unsigned int u = __float_as_uint(f);
    return (unsigned short)((u + 0x7FFFu + ((u >> 16) & 1u)) >> 16);
}
static __device__ __forceinline__ float bh2f(unsigned short h) {
    return __uint_as_float(((unsigned int)h) << 16);
}

// split 8 floats into hi/lo bf16x8 via truncation (residual exact in fp32)
static __device__ __forceinline__ void split_pack(float4 a, float4 b,
                                                  bf16x8& h, bf16x8& l) {
    float f[8] = {a.x, a.y, a.z, a.w, b.x, b.y, b.z, b.w};
    union { bf16x8 v; unsigned int u[4]; } H, L;
    #pragma unroll
    for (int e = 0; e < 4; ++e) {
        unsigned int u0 = __float_as_uint(f[2 * e]);
        unsigned int u1 = __float_as_uint(f[2 * e + 1]);
        H.u[e] = (u0 >> 16) | (u1 & 0xFFFF0000u);
        float r0 = f[2 * e]     - __uint_as_float(u0 & 0xFFFF0000u);
        float r1 = f[2 * e + 1] - __uint_as_float(u1 & 0xFFFF0000u);
        L.u[e] = (__float_as_uint(r0) >> 16) | (__float_as_uint(r1) & 0xFFFF0000u);
    }
    h = H.v; l = L.v;
}

// ------- fused prep: Wg1 chunked image (BK=32) + Wf2 transpose + cursor -----
__global__ __launch_bounds__(256) void k_prep(const float* __restrict__ Wg1,
        const float* __restrict__ Wf2,
        unsigned short* __restrict__ w1img,
        unsigned short* __restrict__ w2h, unsigned short* __restrict__ w2l,
        unsigned int* __restrict__ cursor) {
    int t = blockIdx.x * 256 + threadIdx.x;
    if (t < 65536) {
        int k = t >> 6, c = t & 63;
        float f = Wg1[t];
        unsigned short hh = f2bh(f);
        int chunk = k >> 5, kk = k & 31;
        size_t base = (size_t)chunk * 4608 + (size_t)c * 36 + kk;   // u16 units
        w1img[base] = hh;
        w1img[base + 2304] = f2bh(f - bh2f(hh));
    } else if (t < 131072) {
        int tt = t - 65536;
        int k = tt >> 10, c = tt & 1023;
        float f = Wf2[tt];
        unsigned short hh = f2bh(f);
        w2h[c * 64 + k] = hh;
        w2l[c * 64 + k] = f2bh(f - bh2f(hh));
    } else if (t < 131072 + NN) {
        cursor[t - 131072] = 0u;
    }
}

// -------- bucket fill: bkt[d*64 + pos] = src; cursor ends as degree ---------
__global__ __launch_bounds__(256) void k_fill(const int* __restrict__ src,
        const int* __restrict__ dst, unsigned int* cursor, int* __restrict__ bkt) {
    int e = blockIdx.x * 256 + threadIdx.x;
    if (e < EE) {
        int d = dst[e];
        unsigned int pos = atomicAdd(&cursor[d], 1u);
        bkt[(size_t)d * 64 + pos] = src[e];
    }
}

// -------- bucket sort (64-lane bitonic) + dinv; canonical order -------------
__global__ __launch_bounds__(256) void k_sort(int* __restrict__ bkt,
        const unsigned int* __restrict__ deg, float* __restrict__ dinv) {
    int v = (blockIdx.x * 256 + threadIdx.x) >> 6;
    int lane = threadIdx.x & 63;
    if (v >= NN) return;
    int n = (int)deg[v];
    if (lane == 0) dinv[v] = rsqrtf((float)(n + 1));
    int val = (lane < n) ? bkt[(size_t)v * 64 + lane] : 0x7FFFFFFF;
    #pragma unroll
    for (int k = 2; k <= 64; k <<= 1) {
        #pragma unroll
        for (int j = k >> 1; j > 0; j >>= 1) {
            int partner = __shfl_xor(val, j, 64);
            bool takeMin = (((lane & k) == 0) == ((lane & j) == 0));
            val = takeMin ? min(val, partner) : max(val, partner);
        }
    }
    if (lane < n) bkt[(size_t)v * 64 + lane] = val;
}

// ---------------- GEMM1 v5 (measured best): 64 rows/block, BK=32 ------------
__global__ __launch_bounds__(256) void k_gemm1(const float* __restrict__ x,
        const unsigned short* __restrict__ wimg,
        const float* __restrict__ dinv, unsigned short* __restrict__ g1b) {
    __shared__ __align__(16) unsigned short bs[2][2][64][36];   // 18432 B
    const int tid = threadIdx.x;
    const int lane = tid & 63, w = tid >> 6;
    const int l16 = lane & 15, g = lane >> 4;
    const int row0 = blockIdx.x * 64;
    const int rA = row0 + w * 16 + l16;
    const bool okA = rA < NN;
    const float* xp = x + (size_t)rA * 1024 + g * 8;
    const char* wb = (const char*)wimg;
    f32x4 acc[4] = {};
    for (int j = w; j < 9; j += 4)
        __builtin_amdgcn_global_load_lds((const unsigned int*)(wb + j * 1024 + lane * 16),
                                         (unsigned int*)((char*)&bs[0][0][0][0] + j * 1024), 16, 0, 0);
    float4 xr0 = make_float4(0.f,0.f,0.f,0.f), xr1 = xr0;
    if (okA) { xr0 = *(const float4*)(xp); xr1 = *(const float4*)(xp + 4); }
    __syncthreads();
    int cur = 0;
    for (int t = 0; t < 32; ++t) {
        float4 nx0 = make_float4(0.f,0.f,0.f,0.f), nx1 = nx0;
        if (t < 31) {
            const char* gb = wb + (size_t)(t + 1) * 9216;
            char* lb = (char*)&bs[cur ^ 1][0][0][0];
            for (int j = w; j < 9; j += 4)
                __builtin_amdgcn_global_load_lds((const unsigned int*)(gb + j * 1024 + lane * 16),
                                                 (unsigned int*)(lb + j * 1024), 16, 0, 0);
            if (okA) { nx0 = *(const float4*)(xp + (t + 1) * 32);
                       nx1 = *(const float4*)(xp + (t + 1) * 32 + 4); }
        }
        bf16x8 ah, al;
        split_pack(xr0, xr1, ah, al);
        #pragma unroll
        for (int nf = 0; nf < 4; ++nf) {
            bf16x8 bh = *(const bf16x8*)&bs[cur][0][nf * 16 + l16][g * 8];
            bf16x8 bl = *(const bf16x8*)&bs[cur][1][nf * 16 + l16][g * 8];
            acc[nf] = __builtin_amdgcn_mfma_f32_16x16x32_bf16(ah, bh, acc[nf], 0, 0, 0);
            acc[nf] = __builtin_amdgcn_mfma_f32_16x16x32_bf16(al, bh, acc[nf], 0, 0, 0);
            acc[nf] = __builtin_amdgcn_mfma_f32_16x16x32_bf16(ah, bl, acc[nf], 0, 0, 0);
        }
        __syncthreads();
        xr0 = nx0; xr1 = nx1; cur ^= 1;
    }
    #pragma unroll
    for (int r = 0; r < 4; ++r) {
        int node = row0 + w * 16 + g * 4 + r;
        if (node < NN) {
            float di = dinv[node];
            #pragma unroll
            for (int nf = 0; nf < 4; ++nf)
                g1b[(size_t)node * 64 + nf * 16 + l16] = f2bh(acc[nf][r] * di);
        }
    }
}

// ------- gather 64ch (bf16, half-wave/node): h = relu(dinv*sum + bg1) -------
__global__ __launch_bounds__(256) void k_gather64(const unsigned short* __restrict__ g1b,
        const int* __restrict__ bkt, const unsigned int* __restrict__ deg,
        const float* __restrict__ dinv, const float* __restrict__ bg1,
        float* __restrict__ h) {
    int node = (blockIdx.x * 256 + threadIdx.x) >> 5;   // half-wave = node
    int c = threadIdx.x & 31;                            // channel pair id
    if (node >= NN) return;
    unsigned int n = deg[node];
    const int* b = bkt + (size_t)node * 64;
    const unsigned int* gp = (const unsigned int*)g1b;   // [node][32] uints
    unsigned int self = gp[(size_t)node * 32 + c];
    float sum0 = bh2f((unsigned short)self);
    float sum1 = bh2f((unsigned short)(self >> 16));
    unsigned int i = 0;
    for (; i + 4 <= n; i += 4) {
        int4 s4 = *(const int4*)(b + i);                 // broadcast load
        unsigned int v0 = gp[(size_t)s4.x * 32 + c];
        unsigned int v1 = gp[(size_t)s4.y * 32 + c];
        unsigned int v2 = gp[(size_t)s4.z * 32 + c];
        unsigned int v3 = gp[(size_t)s4.w * 32 + c];
        sum0 += (bh2f((unsigned short)v0) + bh2f((unsigned short)v1))
              + (bh2f((unsigned short)v2) + bh2f((unsigned short)v3));
        sum1 += (bh2f((unsigned short)(v0 >> 16)) + bh2f((unsigned short)(v1 >> 16)))
              + (bh2f((unsigned short)(v2 >> 16)) + bh2f((unsigned short)(v3 >> 16)));
    }
    for (; i < n; ++i) {
        unsigned int v = gp[(size_t)b[i] * 32 + c];
        sum0 += bh2f((unsigned short)v);
        sum1 += bh2f((unsigned short)(v >> 16));
    }
    float di = dinv[node];
    float2 bb = *(const float2*)(bg1 + 2 * c);
    float2 o;
    o.x = fmaxf(sum0 * di + bb.x, 0.f);
    o.y = fmaxf(sum1 * di + bb.y, 0.f);
    *(float2*)(h + (size_t)node * 64 + 2 * c) = o;
}

// ------- layer2 GEMM (fp32): g2b = bf16((h @ Wg2) * dinv[row]) --------------
__global__ __launch_bounds__(256) void k_layer2(const float* __restrict__ h,
        const float* __restrict__ Wg2, const float* __restrict__ dinv,
        unsigned short* __restrict__ g2b) {
    __shared__ __align__(16) float as[64][68];
    __shared__ __align__(16) float wsh[64][32];
    const int tid = threadIdx.x;
    const int node0 = blockIdx.x * 64;
    {
        const int lr = tid >> 4, lk = (tid & 15) * 4;
        #pragma unroll
        for (int l = 0; l < 4; ++l) {
            int r = lr + l * 16, v = node0 + r;
            float4 a = make_float4(0.f, 0.f, 0.f, 0.f);
            if (v < NN) a = *(const float4*)(h + (size_t)v * 64 + lk);
            *(float4*)&as[r][lk] = a;
        }
        const int wr = tid >> 3, wk = (tid & 7) * 4;
        #pragma unroll
        for (int l = 0; l < 2; ++l) {
            int r = wr + l * 32;
            *(float4*)&wsh[r][wk] = *(const float4*)(Wg2 + (size_t)r * 32 + wk);
        }
    }
    __syncthreads();
    const int tx = tid & 7, ty = tid >> 3;
    float acc[2][4] = {{0.f}};
    for (int kk = 0; kk < 64; kk += 4) {
        float wv[4][4];
        #pragma unroll
        for (int j = 0; j < 4; ++j)
            *(float4*)&wv[j][0] = *(const float4*)&wsh[kk + j][tx * 4];
        #pragma unroll
        for (int i = 0; i < 2; ++i) {
            float xv[4];
            *(float4*)&xv[0] = *(const float4*)&as[ty * 2 + i][kk];
            #pragma unroll
            for (int j = 0; j < 4; ++j) {
                #pragma unroll
                for (int c = 0; c < 4; ++c)
                    acc[i][c] += xv[j] * wv[j][c];
            }
        }
    }
    #pragma unroll
    for (int i = 0; i < 2; ++i) {
        int v = node0 + ty * 2 + i;
        if (v < NN) {
            float di = dinv[v];
            unsigned int p0 = (unsigned int)f2bh(acc[i][0] * di)
                            | ((unsigned int)f2bh(acc[i][1] * di) << 16);
            unsigned int p1 = (unsigned int)f2bh(acc[i][2] * di)
                            | ((unsigned int)f2bh(acc[i][3] * di) << 16);
            *(uint2*)(g2b + (size_t)v * 32 + tx * 4) = make_uint2(p0, p1);
        }
    }
}

// ------- gather 32ch (bf16, quarter-wave/node): z = dinv*sum + bg2 ----------
__global__ __launch_bounds__(256) void k_gather32(const unsigned short* __restrict__ g2b,
        const int* __restrict__ bkt, const unsigned int* __restrict__ deg,
        const float* __restrict__ dinv, const float* __restrict__ bg2,
        float* __restrict__ z) {
    int node = (blockIdx.x * 256 + threadIdx.x) >> 4;   // quarter-wave = node
    int c = threadIdx.x & 15;                            // channel pair id
    if (node >= NN) return;
    unsigned int n = deg[node];
    const int* b = bkt + (size_t)node * 64;
    const unsigned int* gp = (const unsigned int*)g2b;   // [node][16] uints
    unsigned int self = gp[(size_t)node * 16 + c];
    float sum0 = bh2f((unsigned short)self);
    float sum1 = bh2f((unsigned short)(self >> 16));
    unsigned int i = 0;
    for (; i + 4 <= n; i += 4) {
        int4 s4 = *(const int4*)(b + i);
        unsigned int v0 = gp[(size_t)s4.x * 16 + c];
        unsigned int v1 = gp[(size_t)s4.y * 16 + c];
        unsigned int v2 = gp[(size_t)s4.z * 16 + c];
        unsigned int v3 = gp[(size_t)s4.w * 16 + c];
        sum0 += (bh2f((unsigned short)v0) + bh2f((unsigned short)v1))
              + (bh2f((unsigned short)v2) + bh2f((unsigned short)v3));
        sum1 += (bh2f((unsigned short)(v0 >> 16)) + bh2f((unsigned short)(v1 >> 16)))
              + (bh2f((unsigned short)(v2 >> 16)) + bh2f((unsigned short)(v3 >> 16)));
    }
    for (; i < n; ++i) {
        unsigned int v = gp[(size_t)b[i] * 16 + c];
        sum0 += bh2f((unsigned short)v);
        sum1 += bh2f((unsigned short)(v >> 16));
    }
    float di = dinv[node];
    float2 bb = *(const float2*)(bg2 + 2 * c);
    float2 o;
    o.x = sum0 * di + bb.x;
    o.y = sum1 * di + bb.y;
    *(float2*)(z + (size_t)node * 32 + 2 * c) = o;
}

// ---------------- decode v3 (r9/r15-measured): 16 chunks x 64 cols ----------
__global__ __launch_bounds__(256) void k_decode(const float* __restrict__ z,
        const float* __restrict__ Wf1, const float* __restrict__ bf1,
        const unsigned short* __restrict__ w2hg, const unsigned short* __restrict__ w2lg,
        const float* __restrict__ bf2, float* __restrict__ out) {
    __shared__ __align__(16) unsigned char smem[35328];
    float (*dsh)[68] = (float (*)[68])smem;                          // 64x68 f
    float (*zs)[36]  = (float (*)[36])(smem + 17408);                // 64x36 f
    float (*w1s)[64] = (float (*)[64])(smem + 26624);                // 32x64 f
    unsigned short (*w2h)[72] = (unsigned short (*)[72])smem;        // 64x72 u16
    unsigned short (*w2l)[72] = (unsigned short (*)[72])(smem + 9216);
    float (*ost)[66] = (float (*)[66])(smem + 18432);                // 64x66 f
    const int tid = threadIdx.x;
    const int lane = tid & 63, w = tid >> 6;
    const int l16 = lane & 15, g = lane >> 4;
    const int node0 = blockIdx.x * 64;

    uint4 ph[2], pl[2];
    #pragma unroll
    for (int j = 0; j < 2; ++j) {
        int fi = tid + 256 * j;
        int c = fi >> 3, k8 = (fi & 7) * 8;
        ph[j] = *(const uint4*)(w2hg + (size_t)c * 64 + k8);
        pl[j] = *(const uint4*)(w2lg + (size_t)c * 64 + k8);
    }

    #pragma unroll
    for (int j = 0; j < 2; ++j) {
        int fi = tid + 256 * j;
        int v = fi >> 3, m4 = (fi & 7) * 4;
        float4 zz = make_float4(0.f, 0.f, 0.f, 0.f);
        if (node0 + v < NN) zz = *(const float4*)(z + (size_t)(node0 + v) * 32 + m4);
        *(float4*)&zs[v][m4] = zz;
    }
    #pragma unroll
    for (int j = 0; j < 2; ++j) {
        int fi = tid + 256 * j;
        int r = fi >> 4, c4 = (fi & 15) * 4;
        *(float4*)&w1s[r][c4] = *(const float4*)(Wf1 + (size_t)r * 64 + c4);
    }
    __syncthreads();

    {
        const int dtx = tid & 15, dty = tid >> 4;
        float acc[4][4] = {{0.f}};
        for (int m = 0; m < 32; m += 4) {
            float wv[4][4];
            #pragma unroll
            for (int j = 0; j < 4; ++j)
                *(float4*)&wv[j][0] = *(const float4*)&w1s[m + j][dtx * 4];
            #pragma unroll
            for (int i = 0; i < 4; ++i) {
                float zv[4];
                *(float4*)&zv[0] = *(const float4*)&zs[dty * 4 + i][m];
                #pragma unroll
                for (int j = 0; j < 4; ++j) {
                    #pragma unroll
                    for (int c = 0; c < 4; ++c)
                        acc[i][c] += zv[j] * wv[j][c];
                }
            }
        }
        float4 b4 = *(const float4*)(bf1 + dtx * 4);
        #pragma unroll
        for (int i = 0; i < 4; ++i) {
            float4 dd;
            dd.x = fmaxf(acc[i][0] + b4.x, 0.f);
            dd.y = fmaxf(acc[i][1] + b4.y, 0.f);
            dd.z = fmaxf(acc[i][2] + b4.z, 0.f);
            dd.w = fmaxf(acc[i][3] + b4.w, 0.f);
            *(float4*)&dsh[dty * 4 + i][dtx * 4] = dd;
        }
    }
    __syncthreads();

    bf16x8 ah[2], al[2];
    {
        int row = w * 16 + l16;
        #pragma unroll
        for (int s = 0; s < 2; ++s) {
            int k0 = s * 32 + g * 8;
            float4 f0 = *(float4*)&dsh[row][k0];
            float4 f1 = *(float4*)&dsh[row][k0 + 4];
            float fv[8] = {f0.x, f0.y, f0.z, f0.w, f1.x, f1.y, f1.z, f1.w};
            bf16x8 hv, lv;
            #pragma unroll
            for (int e = 0; e < 8; ++e) {
                unsigned short hh = f2bh(fv[e]);
                hv[e] = (short)hh;
                lv[e] = (short)f2bh(fv[e] - bh2f(hh));
            }
            ah[s] = hv; al[s] = lv;
        }
    }
    __syncthreads();

    #pragma unroll
    for (int j = 0; j < 2; ++j) {
        int fi = tid + 256 * j;
        int c = fi >> 3, k8 = (fi & 7) * 8;
        *(uint4*)&w2h[c][k8] = ph[j];
        *(uint4*)&w2l[c][k8] = pl[j];
        ph[j] = *(const uint4*)(w2hg + (size_t)(64 + c) * 64 + k8);
        pl[j] = *(const uint4*)(w2lg + (size_t)(64 + c) * 64 + k8);
    }
    __syncthreads();

    for (int ch = 0; ch < 16; ++ch) {
        const int col0 = ch * 64;
        f32x4 acc[4] = {};
        #pragma unroll
        for (int nf = 0; nf < 4; ++nf) {
            int c = nf * 16 + l16;
            #pragma unroll
            for (int s = 0; s < 2; ++s) {
                int k0 = s * 32 + g * 8;
                bf16x8 bh = *(const bf16x8*)&w2h[c][k0];
                bf16x8 bl = *(const bf16x8*)&w2l[c][k0];
                acc[nf] = __builtin_amdgcn_mfma_f32_16x16x32_bf16(ah[s], bh, acc[nf], 0, 0, 0);
                acc[nf] = __builtin_amdgcn_mfma_f32_16x16x32_bf16(al[s], bh, acc[nf], 0, 0, 0);
                acc[nf] = __builtin_amdgcn_mfma_f32_16x16x32_bf16(ah[s], bl, acc[nf], 0, 0, 0);
            }
        }
        #pragma unroll
        for (int nf = 0; nf < 4; ++nf) {
            float b = bf2[col0 + nf * 16 + l16];
            #pragma unroll
            for (int r = 0; r < 4; ++r)
                ost[w * 16 + g * 4 + r][nf * 16 + l16] = fmaxf(acc[nf][r] + b, 0.f);
        }
        __syncthreads();
        if (ch < 15) {
            #pragma unroll
            for (int j = 0; j < 2; ++j) {
                int fi = tid + 256 * j;
                int c = fi >> 3, k8 = (fi & 7) * 8;
                *(uint4*)&w2h[c][k8] = ph[j];
                *(uint4*)&w2l[c][k8] = pl[j];
                if (ch < 14) {
                    ph[j] = *(const uint4*)(w2hg + (size_t)((ch + 2) * 64 + c) * 64 + k8);
                    pl[j] = *(const uint4*)(w2lg + (size_t)((ch + 2) * 64 + c) * 64 + k8);
                }
            }
        }
        #pragma unroll
        for (int j = 0; j < 4; ++j) {
            int fi = tid + 256 * j;
            int row = fi >> 4, c4 = (fi & 15) * 4;
            int node = node0 + row;
            if (node < NN) {
                float4 o = *(float4*)&ost[row][c4];
                *(float4*)(out + (size_t)node * 1024 + col0 + c4) = o;
            }
        }
        __syncthreads();
    }
}

extern "C" void kernel_launch(void* const* d_in, const int* in_sizes, int n_in,
                              void* d_out, int out_size, void* d_ws, size_t ws_size,
                              hipStream_t stream) {
    const float* x   = (const float*)d_in[0];
    const int* ei    = (const int*)d_in[1];
    const float* Wg1 = (const float*)d_in[2];
    const float* bg1 = (const float*)d_in[3];
    const float* Wg2 = (const float*)d_in[4];
    const float* bg2 = (const float*)d_in[5];
    const float* Wf1 = (const float*)d_in[6];
    const float* bf1 = (const float*)d_in[7];
    const float* Wf2 = (const float*)d_in[8];
    const float* bf2 = (const float*)d_in[9];
    float* out = (float*)d_out;
    float* ws  = (float*)d_ws;

    const int* src = ei;
    const int* dst = ei + EE;

    // ws (26 MB): dinv | g2b | z | Wf2T split tables
    float* dinv = ws;
    unsigned short* g2b = (unsigned short*)(ws + NN);              // 32N u16
    float* z    = ws + NN + 16 * NN;
    unsigned short* wf2h = (unsigned short*)(ws + NN + 16 * NN + 32 * NN);  // 64K u16
    unsigned short* wf2l = wf2h + 64 * 1024;                       // 64K u16

    // d_out scratch (all dead before k_decode writes out):
    unsigned short* g1b = (unsigned short*)out;            // 64N u16
    float* h  = out + (size_t)32 * NN;                     // 64N floats
    int* bkt  = (int*)(out + (size_t)96 * NN);             // 64N ints (cap 64)
    unsigned int* cursor = (unsigned int*)(bkt + (size_t)64 * NN);  // N (= degree)
    unsigned short* wg1img = (unsigned short*)(cursor + NN);        // 147456 u16

    k_prep  <<<(131072 + NN + 255) / 256, 256, 0, stream>>>(Wg1, Wf2, wg1img, wf2h, wf2l, cursor);
    k_fill  <<<(EE + 255) / 256, 256, 0, stream>>>(src, dst, cursor, bkt);
    k_sort  <<<(NN * 64 + 255) / 256, 256, 0, stream>>>(bkt, cursor, dinv);
    k_gemm1 <<<(NN + 63) / 64, 256, 0, stream>>>(x, wg1img, dinv, g1b);
    k_gather64<<<(NN * 32 + 255) / 256, 256, 0, stream>>>(g1b, bkt, cursor, dinv, bg1, h);
    k_layer2<<<(NN + 63) / 64, 256, 0, stream>>>(h, Wg2, dinv, g2b);
    k_gather32<<<(NN * 16 + 255) / 256, 256, 0, stream>>>(g2b, bkt, cursor, dinv, bg2, z);
    k_decode<<<(NN + 63) / 64, 256, 0, stream>>>(z, Wf1, bf1, wf2h, wf2l, bf2, out);
}